// Round 10
// baseline (1231.912 us; speedup 1.0000x reference)
//
#include <hip/hip_runtime.h>

#define NATOMS 100000
#define NPAIRS 3200000
// F_ATOM=75, F_PAIR=14, H=50, F_OUT=50

using short8  = __attribute__((ext_vector_type(8))) short;
using float4v = __attribute__((ext_vector_type(4))) float;

__device__ __forceinline__ unsigned short f2bf(float f) {
    unsigned int u = __float_as_uint(f);
    unsigned int r = (u + 0x7fffu + ((u >> 16) & 1u)) >> 16;   // RNE
    return (unsigned short)r;
}
__device__ __forceinline__ float bflo(unsigned int u) { return __uint_as_float(u << 16); }
__device__ __forceinline__ float bfhi(unsigned int u) { return __uint_as_float(u & 0xffff0000u); }
__device__ __forceinline__ unsigned int pack2(float a, float b) {
    return (unsigned int)f2bf(a) | ((unsigned int)f2bf(b) << 16);
}

// ws: AA f32[NATOMS*50] | XAu u32[NATOMS*56] | PAsum f32[NATOMS*50]
//     WPb u16[64*128] (k<50: W_P s-part; k=50: b_P; 52<=k<102: W_P pp-part; else 0)
//     WPPb/WPAb u16[64*32] (k<14: W; k=14: bias; else 0)

__global__ __launch_bounds__(256) void k_wconv(
    const float* __restrict__ W_P,  const float* __restrict__ b_P,
    const float* __restrict__ W_PP, const float* __restrict__ b_PP,
    const float* __restrict__ W_PA, const float* __restrict__ b_PA,
    unsigned short* __restrict__ WPb, unsigned short* __restrict__ WPPb,
    unsigned short* __restrict__ WPAb)
{
    const int idx = blockIdx.x * 256 + threadIdx.x;
    if (idx < 64 * 128) {
        const int n = idx >> 7, k = idx & 127;
        float v = 0.0f;
        if (n < 50) {
            if (k < 50)                  v = W_P[n * 100 + k];
            else if (k == 50)            v = b_P[n];
            else if (k >= 52 && k < 102) v = W_P[n * 100 + 50 + (k - 52)];
        }
        WPb[idx] = f2bf(v);
    }
    if (idx < 64 * 32) {
        const int n = idx >> 5, k = idx & 31;
        float vp = 0.0f, va = 0.0f;
        if (n < 50) {
            if (k < 14)      { vp = W_PP[n * 14 + k]; va = W_PA[n * 14 + k]; }
            else if (k == 14){ vp = b_PP[n];          va = b_PA[n]; }
        }
        WPPb[idx] = f2bf(vp);
        WPAb[idx] = f2bf(va);
    }
}

// K1: per-atom precompute. Coalesced cooperative staging of af into LDS
// (stride 77 f32: odd, coprime with 32 banks -> conflict-free row reads),
// replacing the 300B-lane-stride uncoalesced global reads.
__global__ __launch_bounds__(256) __attribute__((amdgpu_waves_per_eu(2, 2)))
void k_atom_pre(
    const float* __restrict__ af,
    const float* __restrict__ W_AA, const float* __restrict__ b_AA,
    const float* __restrict__ W_AP, const float* __restrict__ b_AP,
    float* __restrict__ AA, unsigned int* __restrict__ XAu)
{
    __shared__ float xs[128 * 77];
    const int blk = blockIdx.x;
    const int a0b = blk * 128;
    const int nv  = (NATOMS - a0b < 128) ? (NATOMS - a0b) : 128;

    {
        const float* src = af + (size_t)a0b * 75;
        const int tot = nv * 75;
        for (int idx = threadIdx.x; idx < tot; idx += 256) {
            const int r = idx / 75, c = idx - r * 75;
            xs[r * 77 + c] = src[idx];
        }
    }
    __syncthreads();

    const int al   = threadIdx.x & 127;
    const int half = threadIdx.x >> 7;
    if (al >= nv) return;
    const int a = a0b + al;

    float x[75];
#pragma unroll
    for (int k = 0; k < 75; ++k) x[k] = xs[al * 77 + k];

    const int jbase = half ? 26 : 0;
    const int jend  = half ? 50 : 26;

    float* aout = AA + (size_t)a * 50;
#pragma unroll 2
    for (int j = jbase; j < jend; ++j) {
        const float* wr = W_AA + (size_t)j * 75;
        float acc = b_AA[j];
#pragma unroll
        for (int k = 0; k < 75; ++k) acc = fmaf(x[k], wr[k], acc);
        aout[j] = fmaxf(acc, 0.0f);
    }

    unsigned int* xout = XAu + (size_t)a * 56;
    const int nu    = half ? 12 : 13;
    const int ubase = half ? 13 : 0;
#pragma unroll 1
    for (int u = 0; u < nu; ++u) {
        const int j = jbase + 2 * u;
        const float2* w0 = (const float2*)(W_AP + (size_t)j * 150);
        const float2* w1 = (const float2*)(W_AP + (size_t)(j + 1) * 150);
        float a0 = b_AP[j], a1 = b_AP[j + 1];
        float c0 = 0.0f,   c1 = 0.0f;
#pragma unroll
        for (int q = 0; q < 37; ++q) {
            float2 wa = w0[q], wb = w1[q];
            a0 = fmaf(x[2 * q], wa.x, a0); a0 = fmaf(x[2 * q + 1], wa.y, a0);
            a1 = fmaf(x[2 * q], wb.x, a1); a1 = fmaf(x[2 * q + 1], wb.y, a1);
        }
        a0 = fmaf(x[74], ((const float*)w0)[74], a0);
        a1 = fmaf(x[74], ((const float*)w1)[74], a1);
        c0 = fmaf(x[0], ((const float*)w0)[75], c0);
        c1 = fmaf(x[0], ((const float*)w1)[75], c1);
#pragma unroll
        for (int q = 0; q < 37; ++q) {
            float2 wa = ((const float2*)(((const float*)w0) + 76))[q];
            float2 wb = ((const float2*)(((const float*)w1) + 76))[q];
            c0 = fmaf(x[2 * q + 1], wa.x, c0); c0 = fmaf(x[2 * q + 2], wa.y, c0);
            c1 = fmaf(x[2 * q + 1], wb.x, c1); c1 = fmaf(x[2 * q + 2], wb.y, c1);
        }
        xout[ubase + u]      = pack2(a0, a1);
        xout[28 + ubase + u] = pack2(c0, c1);
    }
}

__device__ __forceinline__ void s_chunk(
    uint4 A, uint4 B, uint4 C, uint4 D, int c, unsigned int* srow, int swz)
{
    float e0 = fmaxf(bflo(A.x) + bflo(B.x), 0.f) + fmaxf(bflo(C.x) + bflo(D.x), 0.f);
    float e1 = fmaxf(bfhi(A.x) + bfhi(B.x), 0.f) + fmaxf(bfhi(C.x) + bfhi(D.x), 0.f);
    float e2 = fmaxf(bflo(A.y) + bflo(B.y), 0.f) + fmaxf(bflo(C.y) + bflo(D.y), 0.f);
    float e3 = fmaxf(bfhi(A.y) + bfhi(B.y), 0.f) + fmaxf(bfhi(C.y) + bfhi(D.y), 0.f);
    float e4 = fmaxf(bflo(A.z) + bflo(B.z), 0.f) + fmaxf(bflo(C.z) + bflo(D.z), 0.f);
    float e5 = fmaxf(bfhi(A.z) + bfhi(B.z), 0.f) + fmaxf(bfhi(C.z) + bfhi(D.z), 0.f);
    float e6 = fmaxf(bflo(A.w) + bflo(B.w), 0.f) + fmaxf(bflo(C.w) + bflo(D.w), 0.f);
    float e7 = fmaxf(bfhi(A.w) + bfhi(B.w), 0.f) + fmaxf(bfhi(C.w) + bfhi(D.w), 0.f);
    srow[(4 * c + 0) ^ swz] = pack2(e0, e1);
    srow[(4 * c + 1) ^ swz] = pack2(e2, e3);
    srow[(4 * c + 2) ^ swz] = pack2(e4, e5);
    srow[(4 * c + 3) ^ swz] = pack2(e6, e7);
}

// K2: MFMA pair kernel. S rows = 256B, U rows = 128B (stride % 128B == 0 so
// rows contribute nothing to bank index), pure XOR swizzle byte^=(row&7)<<4
// -> 2 lanes/bank (free) on all b128/b64 LDS traffic. Segment-reduce walk
// capped at 32 rows via forced heads every 32 rows.
__global__ __launch_bounds__(512) void k_pair(
    const float* __restrict__ pf,
    const int* __restrict__ psplit,
    const int* __restrict__ a2p,
    const unsigned short* __restrict__ WPb,
    const unsigned short* __restrict__ WPPb,
    const unsigned short* __restrict__ WPAb,
    const unsigned int* __restrict__ XAu,
    float* __restrict__ PAsum,
    float* __restrict__ Pout)
{
    // S row (64 u32): 0..24 s(k0..49), 25 = (1.0,0) bias slot, 26..50 pp, 51..63 zero
    __shared__ unsigned int  S32[128 * 64];   // 32 KB
    // U row (64 u16): staging pf (k0..31) then PA (n0..49)
    __shared__ unsigned short U16[128 * 64];  // 16 KB
    __shared__ int ps_lds[128];
    __shared__ unsigned char head_list[128];
    __shared__ int nheads;

    const int t   = threadIdx.x;
    const int blk = blockIdx.x;
    const int pl  = t >> 2;
    const int sub = t & 3;
    const int p   = blk * 128 + pl;   // NPAIRS == 25000*128
    const int w   = t >> 6;
    const int l   = t & 63;
    const int lr  = l & 15;
    const int lk  = l >> 4;

    if (t == 0) nheads = 0;
    if (t < 128) ps_lds[t] = psplit[blk * 128 + t];

    // early independent loads
    const int2 ij = ((const int2*)a2p)[p];
    float2 pfa, pfb, pfc, pfd;
    {
        const float2* pr2 = (const float2*)(pf + (size_t)p * 14);
        if (sub == 0) { pfa = pr2[0]; pfb = pr2[1]; pfc = pr2[2]; pfd = pr2[3]; }
        else if (sub == 1) { pfa = pr2[4]; pfb = pr2[5]; pfc = pr2[6]; }
    }

    // gather (issued as soon as ij lands)
    const uint4* xi4 = (const uint4*)(XAu + (size_t)ij.x * 56);
    const uint4* xj4 = (const uint4*)(XAu + (size_t)ij.y * 56);
    uint4 A0 = xi4[sub], B0 = xj4[7 + sub], C0 = xj4[sub], D0 = xi4[7 + sub];
    uint4 A1, B1, C1, D1;
    unsigned int tA = 0, tB = 0, tC = 0, tD = 0;
    if (sub < 2) { A1 = xi4[4 + sub]; B1 = xj4[11 + sub]; C1 = xj4[4 + sub]; D1 = xi4[11 + sub]; }
    if (sub == 2) {
        const unsigned int* xiu = (const unsigned int*)xi4;
        const unsigned int* xju = (const unsigned int*)xj4;
        tA = xiu[24]; tB = xju[52]; tC = xju[24]; tD = xiu[52];
    }

    // stage pf -> U row pl (k0..13 = pf, k14 = 1.0, k15..31 = 0)
    {
        uint4 q = {0u, 0u, 0u, 0u};
        if (sub == 0) {
            q.x = pack2(pfa.x, pfa.y); q.y = pack2(pfb.x, pfb.y);
            q.z = pack2(pfc.x, pfc.y); q.w = pack2(pfd.x, pfd.y);
        } else if (sub == 1) {
            q.x = pack2(pfa.x, pfa.y); q.y = pack2(pfb.x, pfb.y);
            q.z = pack2(pfc.x, pfc.y); q.w = 0x00003F80u;   // k14=1.0, k15=0
        }
        *(uint4*)((char*)U16 + pl * 128 + ((16 * sub) ^ ((pl & 7) << 4))) = q;
    }

    // s -> S row pl (swizzled u32 writes)
    {
        unsigned int* srow = &S32[pl * 64];
        const int swz = (pl & 7) << 2;
        s_chunk(A0, B0, C0, D0, sub, srow, swz);
        if (sub < 2) s_chunk(A1, B1, C1, D1, 4 + sub, srow, swz);
        if (sub == 2) {
            float s48 = fmaxf(bflo(tA) + bflo(tB), 0.f) + fmaxf(bflo(tC) + bflo(tD), 0.f);
            float s49 = fmaxf(bfhi(tA) + bfhi(tB), 0.f) + fmaxf(bfhi(tC) + bfhi(tD), 0.f);
            srow[24 ^ swz] = pack2(s48, s49);
        }
        if (sub == 1) srow[25 ^ swz] = 0x00003F80u;   // k50=1.0, k51=0
#pragma unroll
        for (int i = 0; i < 4; ++i) {
            const int u = 51 + sub + 4 * i;
            if (u <= 63) srow[u ^ swz] = 0u;
        }
    }

    // PP & PA MFMA (A = W tiles, B = pf fragment; D[n][pair])
    {
        const int row  = 16 * w + lr;
        const int swz4 = (row & 7) << 2;
        const short8 bfrag = *(const short8*)((const char*)U16 + row * 128 + ((16 * lk) ^ ((row & 7) << 4)));
        unsigned int* srow = &S32[row * 64];
        unsigned int* U32  = (unsigned int*)U16;

#pragma unroll
        for (int nt = 0; nt < 4; ++nt) {
            short8 afr = *(const short8*)(WPPb + (nt * 16 + lr) * 32 + lk * 8);
            float4v acc = __builtin_amdgcn_mfma_f32_16x16x32_bf16(
                afr, bfrag, (float4v){0.f, 0.f, 0.f, 0.f}, 0, 0, 0);
            const int n0 = nt * 16 + lk * 4;
            if (n0 < 48) {
                uint2 v;
                v.x = pack2(fmaxf(acc[0], 0.f), fmaxf(acc[1], 0.f));
                v.y = pack2(fmaxf(acc[2], 0.f), fmaxf(acc[3], 0.f));
                *(uint2*)&srow[(26 + (n0 >> 1)) ^ swz4] = v;
            } else if (lk == 0) {
                srow[50 ^ swz4] = pack2(fmaxf(acc[0], 0.f), fmaxf(acc[1], 0.f));
            }
        }
#pragma unroll
        for (int nt = 0; nt < 4; ++nt) {
            short8 afr = *(const short8*)(WPAb + (nt * 16 + lr) * 32 + lk * 8);
            float4v acc = __builtin_amdgcn_mfma_f32_16x16x32_bf16(
                afr, bfrag, (float4v){0.f, 0.f, 0.f, 0.f}, 0, 0, 0);
            const int n0 = nt * 16 + lk * 4;
            if (n0 < 48) {
                uint2 v;
                v.x = pack2(fmaxf(acc[0], 0.f), fmaxf(acc[1], 0.f));
                v.y = pack2(fmaxf(acc[2], 0.f), fmaxf(acc[3], 0.f));
                *(uint2*)&U32[row * 32 + (((n0 >> 1)) ^ swz4)] = v;
            } else if (lk == 0) {
                U32[row * 32 + (24 ^ swz4)] = pack2(fmaxf(acc[0], 0.f), fmaxf(acc[1], 0.f));
            }
        }
    }

    // P GEMM: A = WPb tiles, B = S fragments; D[n][pair] -> float2 stores
    {
        const int row = 16 * w + lr;
        short8 sfrag[4];
        const char* srowb = (const char*)&S32[row * 64];
#pragma unroll
        for (int ks = 0; ks < 4; ++ks)
            sfrag[ks] = *(const short8*)(srowb + ((64 * ks + 16 * lk) ^ ((row & 7) << 4)));
        float* po = Pout + ((size_t)blk * 128 + row) * 50;
#pragma unroll
        for (int nt = 0; nt < 4; ++nt) {
            float4v acc = {0.f, 0.f, 0.f, 0.f};
#pragma unroll
            for (int ks = 0; ks < 4; ++ks) {
                short8 wf = *(const short8*)(WPb + (nt * 16 + lr) * 128 + ks * 32 + lk * 8);
                acc = __builtin_amdgcn_mfma_f32_16x16x32_bf16(wf, sfrag[ks], acc, 0, 0, 0);
            }
            const int n0 = nt * 16 + lk * 4;
            if (n0 < 48) {
                float2 v0 = {fmaxf(acc[0], 0.f), fmaxf(acc[1], 0.f)};
                float2 v1 = {fmaxf(acc[2], 0.f), fmaxf(acc[3], 0.f)};
                *(float2*)(po + n0)     = v0;
                *(float2*)(po + n0 + 2) = v1;
            } else if (lk == 0) {
                float2 v0 = {fmaxf(acc[0], 0.f), fmaxf(acc[1], 0.f)};
                *(float2*)(po + 48) = v0;
            }
        }
    }

    // segment-sum of PA; forced heads every 32 rows cap the serial walk
    __syncthreads();
    if (t < 128) {
        bool head = ((t & 31) == 0) || (ps_lds[t] != ps_lds[t - 1]);
        if (head) {
            int idx = atomicAdd(&nheads, 1);
            head_list[idx] = (unsigned char)t;
        }
    }
    __syncthreads();

    const int nh = nheads;
    const unsigned int* U32c = (const unsigned int*)U16;
    for (int iw = t; iw < nh * 25; iw += 512) {
        const int r0  = head_list[iw / 25];
        const int jc  = iw % 25;
        const int seg = ps_lds[r0];
        float a0 = 0.0f, a1 = 0.0f;
        int rr = r0;
        do {
            unsigned int u = U32c[rr * 32 + (jc ^ ((rr & 7) << 2))];
            a0 += bflo(u);
            a1 += bfhi(u);
            ++rr;
        } while (rr < 128 && (rr & 31) != 0 && ps_lds[rr] == seg);
        atomicAdd(&PAsum[(size_t)seg * 50 + 2 * jc],     a0);
        atomicAdd(&PAsum[(size_t)seg * 50 + 2 * jc + 1], a1);
    }
}

// K3: A = relu(concat(AA, PAsum) @ W_A.T + b_A). Coalesced LDS staging
// (stride 101 f32, coprime with 32) replaces 200/400B-stride lane reads.
__global__ __launch_bounds__(256) __attribute__((amdgpu_waves_per_eu(2, 2)))
void k_atom_final(
    const float* __restrict__ AA, const float* __restrict__ PAsum,
    const float* __restrict__ W_A, const float* __restrict__ b_A,
    float* __restrict__ Aout)
{
    __shared__ float vs[128 * 101];
    const int blk = blockIdx.x;
    const int a0b = blk * 128;
    const int nv  = (NATOMS - a0b < 128) ? (NATOMS - a0b) : 128;

    {
        const float* s1 = AA    + (size_t)a0b * 50;
        const float* s2 = PAsum + (size_t)a0b * 50;
        const int tot = nv * 50;
        for (int idx = threadIdx.x; idx < tot; idx += 256) {
            const int r = idx / 50, c = idx - r * 50;
            vs[r * 101 + c]      = s1[idx];
            vs[r * 101 + 50 + c] = s2[idx];
        }
    }
    __syncthreads();

    const int al   = threadIdx.x & 127;
    const int half = threadIdx.x >> 7;
    if (al >= nv) return;
    const int a  = a0b + al;
    const int o0 = half * 25;

    float v[100];
#pragma unroll
    for (int f = 0; f < 100; ++f) v[f] = vs[al * 101 + f];

    float* ao = Aout + (size_t)a * 50;
#pragma unroll 2
    for (int o = o0; o < o0 + 25; ++o) {
        const float4* w4 = (const float4*)(W_A + (size_t)o * 100);
        float acc = b_A[o];
#pragma unroll
        for (int q = 0; q < 25; ++q) {
            float4 w = w4[q];
            acc = fmaf(v[4 * q + 0], w.x, acc);
            acc = fmaf(v[4 * q + 1], w.y, acc);
            acc = fmaf(v[4 * q + 2], w.z, acc);
            acc = fmaf(v[4 * q + 3], w.w, acc);
        }
        ao[o] = fmaxf(acc, 0.0f);
    }
}

extern "C" void kernel_launch(void* const* d_in, const int* in_sizes, int n_in,
                              void* d_out, int out_size, void* d_ws, size_t ws_size,
                              hipStream_t stream)
{
    const float* atom_features = (const float*)d_in[0];
    const float* pair_features = (const float*)d_in[1];
    const int*   pair_split    = (const int*)d_in[2];
    const int*   atom_to_pair  = (const int*)d_in[3];
    const float* W_AA = (const float*)d_in[4];
    const float* b_AA = (const float*)d_in[5];
    const float* W_PA = (const float*)d_in[6];
    const float* b_PA = (const float*)d_in[7];
    const float* W_A  = (const float*)d_in[8];
    const float* b_A  = (const float*)d_in[9];
    const float* W_AP = (const float*)d_in[10];
    const float* b_AP = (const float*)d_in[11];
    const float* W_PP = (const float*)d_in[12];
    const float* b_PP = (const float*)d_in[13];
    const float* W_P  = (const float*)d_in[14];
    const float* b_P  = (const float*)d_in[15];

    float* out   = (float*)d_out;
    float* A_out = out;                              // [NATOMS,50]
    float* P_out = out + (size_t)NATOMS * 50;        // [NPAIRS,50]

    float*          AA    = (float*)d_ws;                               // 5,000,000 f32
    unsigned int*   XAu   = (unsigned int*)(AA + (size_t)NATOMS * 50);  // 5,600,000 u32
    float*          PAsum = (float*)(XAu + (size_t)NATOMS * 56);        // 5,000,000 f32
    unsigned short* WPb   = (unsigned short*)(PAsum + (size_t)NATOMS * 50);  // 8192 u16
    unsigned short* WPPb  = WPb + 64 * 128;                                  // 2048 u16
    unsigned short* WPAb  = WPPb + 64 * 32;                                  // 2048 u16

    hipMemsetAsync(PAsum, 0, (size_t)NATOMS * 50 * sizeof(float), stream);

    k_wconv<<<32, 256, 0, stream>>>(W_P, b_P, W_PP, b_PP, W_PA, b_PA, WPb, WPPb, WPAb);

    k_atom_pre<<<(NATOMS + 127) / 128, 256, 0, stream>>>(
        atom_features, W_AA, b_AA, W_AP, b_AP, AA, XAu);

    k_pair<<<NPAIRS / 128, 512, 0, stream>>>(
        pair_features, pair_split, atom_to_pair,
        WPb, WPPb, WPAb, XAu, PAsum, P_out);

    k_atom_final<<<(NATOMS + 127) / 128, 256, 0, stream>>>(
        AA, PAsum, W_A, b_A, A_out);
}

// Round 11
// 1097.035 us; speedup vs baseline: 1.1229x; 1.1229x over previous
//
#include <hip/hip_runtime.h>

#define NATOMS 100000
#define NPAIRS 3200000
// F_ATOM=75, F_PAIR=14, H=50, F_OUT=50

using short8  = __attribute__((ext_vector_type(8))) short;
using float4v = __attribute__((ext_vector_type(4))) float;

__device__ __forceinline__ unsigned short f2bf(float f) {
    unsigned int u = __float_as_uint(f);
    unsigned int r = (u + 0x7fffu + ((u >> 16) & 1u)) >> 16;   // RNE
    return (unsigned short)r;
}
__device__ __forceinline__ float bflo(unsigned int u) { return __uint_as_float(u << 16); }
__device__ __forceinline__ float bfhi(unsigned int u) { return __uint_as_float(u & 0xffff0000u); }
// HW packed conversion: one VALU op for 2 f32 -> 2 bf16 (RNE). No builtin on gfx950.
__device__ __forceinline__ unsigned int cvtpk(float lo, float hi) {
    unsigned int r;
    asm("v_cvt_pk_bf16_f32 %0, %1, %2" : "=v"(r) : "v"(lo), "v"(hi));
    return r;
}

// ws: AA f32[NATOMS*50] | XAu u32[NATOMS*56] | PAsum f32[NATOMS*50]
//     WPb u16[64*128] (k<50: W_P s-part; k=50: b_P; 52<=k<102: W_P pp-part; else 0)
//     WPPb/WPAb u16[64*32] (k<14: W; k=14: bias; else 0)

__global__ __launch_bounds__(256) void k_wconv(
    const float* __restrict__ W_P,  const float* __restrict__ b_P,
    const float* __restrict__ W_PP, const float* __restrict__ b_PP,
    const float* __restrict__ W_PA, const float* __restrict__ b_PA,
    unsigned short* __restrict__ WPb, unsigned short* __restrict__ WPPb,
    unsigned short* __restrict__ WPAb)
{
    const int idx = blockIdx.x * 256 + threadIdx.x;
    if (idx < 64 * 128) {
        const int n = idx >> 7, k = idx & 127;
        float v = 0.0f;
        if (n < 50) {
            if (k < 50)                  v = W_P[n * 100 + k];
            else if (k == 50)            v = b_P[n];
            else if (k >= 52 && k < 102) v = W_P[n * 100 + 50 + (k - 52)];
        }
        WPb[idx] = f2bf(v);
    }
    if (idx < 64 * 32) {
        const int n = idx >> 5, k = idx & 31;
        float vp = 0.0f, va = 0.0f;
        if (n < 50) {
            if (k < 14)      { vp = W_PP[n * 14 + k]; va = W_PA[n * 14 + k]; }
            else if (k == 14){ vp = b_PP[n];          va = b_PA[n]; }
        }
        WPPb[idx] = f2bf(vp);
        WPAb[idx] = f2bf(va);
    }
}

// K1: per-atom precompute (round-9 form — LDS staging variant regressed).
__global__ __launch_bounds__(256) __attribute__((amdgpu_waves_per_eu(2, 2)))
void k_atom_pre(
    const float* __restrict__ af,
    const float* __restrict__ W_AA, const float* __restrict__ b_AA,
    const float* __restrict__ W_AP, const float* __restrict__ b_AP,
    float* __restrict__ AA, unsigned int* __restrict__ XAu)
{
    const int a = blockIdx.x * 256 + threadIdx.x;
    if (a >= NATOMS) return;
    const int half = blockIdx.y;

    const float* ar = af + (size_t)a * 75;
    float x[75];
#pragma unroll
    for (int k = 0; k < 75; ++k) x[k] = ar[k];

    const int jbase = half ? 26 : 0;
    const int jend  = half ? 50 : 26;

    float* aout = AA + (size_t)a * 50;
#pragma unroll 2
    for (int j = jbase; j < jend; ++j) {
        const float* wr = W_AA + (size_t)j * 75;
        float acc = b_AA[j];
#pragma unroll
        for (int k = 0; k < 75; ++k) acc = fmaf(x[k], wr[k], acc);
        aout[j] = fmaxf(acc, 0.0f);
    }

    unsigned int* xout = XAu + (size_t)a * 56;
    const int nu    = half ? 12 : 13;
    const int ubase = half ? 13 : 0;
#pragma unroll 1
    for (int u = 0; u < nu; ++u) {
        const int j = jbase + 2 * u;
        const float2* w0 = (const float2*)(W_AP + (size_t)j * 150);
        const float2* w1 = (const float2*)(W_AP + (size_t)(j + 1) * 150);
        float a0 = b_AP[j], a1 = b_AP[j + 1];
        float c0 = 0.0f,   c1 = 0.0f;
#pragma unroll
        for (int q = 0; q < 37; ++q) {
            float2 wa = w0[q], wb = w1[q];
            a0 = fmaf(x[2 * q], wa.x, a0); a0 = fmaf(x[2 * q + 1], wa.y, a0);
            a1 = fmaf(x[2 * q], wb.x, a1); a1 = fmaf(x[2 * q + 1], wb.y, a1);
        }
        a0 = fmaf(x[74], ((const float*)w0)[74], a0);
        a1 = fmaf(x[74], ((const float*)w1)[74], a1);
        c0 = fmaf(x[0], ((const float*)w0)[75], c0);
        c1 = fmaf(x[0], ((const float*)w1)[75], c1);
#pragma unroll
        for (int q = 0; q < 37; ++q) {
            float2 wa = ((const float2*)(((const float*)w0) + 76))[q];
            float2 wb = ((const float2*)(((const float*)w1) + 76))[q];
            c0 = fmaf(x[2 * q + 1], wa.x, c0); c0 = fmaf(x[2 * q + 2], wa.y, c0);
            c1 = fmaf(x[2 * q + 1], wb.x, c1); c1 = fmaf(x[2 * q + 2], wb.y, c1);
        }
        xout[ubase + u]      = cvtpk(a0, a1);
        xout[28 + ubase + u] = cvtpk(c0, c1);
    }
}

__device__ __forceinline__ void s_chunk(
    uint4 A, uint4 B, uint4 C, uint4 D, int c, unsigned int* srow, int swz)
{
    float e0 = fmaxf(bflo(A.x) + bflo(B.x), 0.f) + fmaxf(bflo(C.x) + bflo(D.x), 0.f);
    float e1 = fmaxf(bfhi(A.x) + bfhi(B.x), 0.f) + fmaxf(bfhi(C.x) + bfhi(D.x), 0.f);
    float e2 = fmaxf(bflo(A.y) + bflo(B.y), 0.f) + fmaxf(bflo(C.y) + bflo(D.y), 0.f);
    float e3 = fmaxf(bfhi(A.y) + bfhi(B.y), 0.f) + fmaxf(bfhi(C.y) + bfhi(D.y), 0.f);
    float e4 = fmaxf(bflo(A.z) + bflo(B.z), 0.f) + fmaxf(bflo(C.z) + bflo(D.z), 0.f);
    float e5 = fmaxf(bfhi(A.z) + bfhi(B.z), 0.f) + fmaxf(bfhi(C.z) + bfhi(D.z), 0.f);
    float e6 = fmaxf(bflo(A.w) + bflo(B.w), 0.f) + fmaxf(bflo(C.w) + bflo(D.w), 0.f);
    float e7 = fmaxf(bfhi(A.w) + bfhi(B.w), 0.f) + fmaxf(bfhi(C.w) + bfhi(D.w), 0.f);
    srow[(4 * c + 0) ^ swz] = cvtpk(e0, e1);
    srow[(4 * c + 1) ^ swz] = cvtpk(e2, e3);
    srow[(4 * c + 2) ^ swz] = cvtpk(e4, e5);
    srow[(4 * c + 3) ^ swz] = cvtpk(e6, e7);
}

// K2: MFMA pair kernel (round-10 structure; all bf16 packing now via
// v_cvt_pk_bf16_f32 — one VALU op instead of ~9).
__global__ __launch_bounds__(512) void k_pair(
    const float* __restrict__ pf,
    const int* __restrict__ psplit,
    const int* __restrict__ a2p,
    const unsigned short* __restrict__ WPb,
    const unsigned short* __restrict__ WPPb,
    const unsigned short* __restrict__ WPAb,
    const unsigned int* __restrict__ XAu,
    float* __restrict__ PAsum,
    float* __restrict__ Pout)
{
    // S row (64 u32): 0..24 s(k0..49), 25 = (1.0,0) bias slot, 26..50 pp, 51..63 zero
    __shared__ unsigned int  S32[128 * 64];   // 32 KB
    // U row (64 u16): staging pf (k0..31) then PA (n0..49)
    __shared__ unsigned short U16[128 * 64];  // 16 KB
    __shared__ int ps_lds[128];
    __shared__ unsigned char head_list[128];
    __shared__ int nheads;

    const int t   = threadIdx.x;
    const int blk = blockIdx.x;
    const int pl  = t >> 2;
    const int sub = t & 3;
    const int p   = blk * 128 + pl;   // NPAIRS == 25000*128
    const int w   = t >> 6;
    const int l   = t & 63;
    const int lr  = l & 15;
    const int lk  = l >> 4;

    if (t == 0) nheads = 0;
    if (t < 128) ps_lds[t] = psplit[blk * 128 + t];

    // early independent loads
    const int2 ij = ((const int2*)a2p)[p];
    float2 pfa, pfb, pfc, pfd;
    {
        const float2* pr2 = (const float2*)(pf + (size_t)p * 14);
        if (sub == 0) { pfa = pr2[0]; pfb = pr2[1]; pfc = pr2[2]; pfd = pr2[3]; }
        else if (sub == 1) { pfa = pr2[4]; pfb = pr2[5]; pfc = pr2[6]; }
    }

    // gather (issued as soon as ij lands)
    const uint4* xi4 = (const uint4*)(XAu + (size_t)ij.x * 56);
    const uint4* xj4 = (const uint4*)(XAu + (size_t)ij.y * 56);
    uint4 A0 = xi4[sub], B0 = xj4[7 + sub], C0 = xj4[sub], D0 = xi4[7 + sub];
    uint4 A1, B1, C1, D1;
    unsigned int tA = 0, tB = 0, tC = 0, tD = 0;
    if (sub < 2) { A1 = xi4[4 + sub]; B1 = xj4[11 + sub]; C1 = xj4[4 + sub]; D1 = xi4[11 + sub]; }
    if (sub == 2) {
        const unsigned int* xiu = (const unsigned int*)xi4;
        const unsigned int* xju = (const unsigned int*)xj4;
        tA = xiu[24]; tB = xju[52]; tC = xju[24]; tD = xiu[52];
    }

    // stage pf -> U row pl (k0..13 = pf, k14 = 1.0, k15..31 = 0)
    {
        uint4 q = {0u, 0u, 0u, 0u};
        if (sub == 0) {
            q.x = cvtpk(pfa.x, pfa.y); q.y = cvtpk(pfb.x, pfb.y);
            q.z = cvtpk(pfc.x, pfc.y); q.w = cvtpk(pfd.x, pfd.y);
        } else if (sub == 1) {
            q.x = cvtpk(pfa.x, pfa.y); q.y = cvtpk(pfb.x, pfb.y);
            q.z = cvtpk(pfc.x, pfc.y); q.w = 0x00003F80u;   // k14=1.0, k15=0
        }
        *(uint4*)((char*)U16 + pl * 128 + ((16 * sub) ^ ((pl & 7) << 4))) = q;
    }

    // s -> S row pl (swizzled u32 writes)
    {
        unsigned int* srow = &S32[pl * 64];
        const int swz = (pl & 7) << 2;
        s_chunk(A0, B0, C0, D0, sub, srow, swz);
        if (sub < 2) s_chunk(A1, B1, C1, D1, 4 + sub, srow, swz);
        if (sub == 2) {
            float s48 = fmaxf(bflo(tA) + bflo(tB), 0.f) + fmaxf(bflo(tC) + bflo(tD), 0.f);
            float s49 = fmaxf(bfhi(tA) + bfhi(tB), 0.f) + fmaxf(bfhi(tC) + bfhi(tD), 0.f);
            srow[24 ^ swz] = cvtpk(s48, s49);
        }
        if (sub == 1) srow[25 ^ swz] = 0x00003F80u;   // k50=1.0, k51=0
#pragma unroll
        for (int i = 0; i < 4; ++i) {
            const int u = 51 + sub + 4 * i;
            if (u <= 63) srow[u ^ swz] = 0u;
        }
    }

    // PP & PA MFMA (A = W tiles, B = pf fragment; D[n][pair])
    {
        const int row  = 16 * w + lr;
        const int swz4 = (row & 7) << 2;
        const short8 bfrag = *(const short8*)((const char*)U16 + row * 128 + ((16 * lk) ^ ((row & 7) << 4)));
        unsigned int* srow = &S32[row * 64];
        unsigned int* U32  = (unsigned int*)U16;

#pragma unroll
        for (int nt = 0; nt < 4; ++nt) {
            short8 afr = *(const short8*)(WPPb + (nt * 16 + lr) * 32 + lk * 8);
            float4v acc = __builtin_amdgcn_mfma_f32_16x16x32_bf16(
                afr, bfrag, (float4v){0.f, 0.f, 0.f, 0.f}, 0, 0, 0);
            const int n0 = nt * 16 + lk * 4;
            if (n0 < 48) {
                uint2 v;
                v.x = cvtpk(fmaxf(acc[0], 0.f), fmaxf(acc[1], 0.f));
                v.y = cvtpk(fmaxf(acc[2], 0.f), fmaxf(acc[3], 0.f));
                *(uint2*)&srow[(26 + (n0 >> 1)) ^ swz4] = v;
            } else if (lk == 0) {
                srow[50 ^ swz4] = cvtpk(fmaxf(acc[0], 0.f), fmaxf(acc[1], 0.f));
            }
        }
#pragma unroll
        for (int nt = 0; nt < 4; ++nt) {
            short8 afr = *(const short8*)(WPAb + (nt * 16 + lr) * 32 + lk * 8);
            float4v acc = __builtin_amdgcn_mfma_f32_16x16x32_bf16(
                afr, bfrag, (float4v){0.f, 0.f, 0.f, 0.f}, 0, 0, 0);
            const int n0 = nt * 16 + lk * 4;
            if (n0 < 48) {
                uint2 v;
                v.x = cvtpk(fmaxf(acc[0], 0.f), fmaxf(acc[1], 0.f));
                v.y = cvtpk(fmaxf(acc[2], 0.f), fmaxf(acc[3], 0.f));
                *(uint2*)&U32[row * 32 + (((n0 >> 1)) ^ swz4)] = v;
            } else if (lk == 0) {
                U32[row * 32 + (24 ^ swz4)] = cvtpk(fmaxf(acc[0], 0.f), fmaxf(acc[1], 0.f));
            }
        }
    }

    // P GEMM: A = WPb tiles, B = S fragments; D[n][pair] -> float2 stores
    {
        const int row = 16 * w + lr;
        short8 sfrag[4];
        const char* srowb = (const char*)&S32[row * 64];
#pragma unroll
        for (int ks = 0; ks < 4; ++ks)
            sfrag[ks] = *(const short8*)(srowb + ((64 * ks + 16 * lk) ^ ((row & 7) << 4)));
        float* po = Pout + ((size_t)blk * 128 + row) * 50;
#pragma unroll
        for (int nt = 0; nt < 4; ++nt) {
            float4v acc = {0.f, 0.f, 0.f, 0.f};
#pragma unroll
            for (int ks = 0; ks < 4; ++ks) {
                short8 wf = *(const short8*)(WPb + (nt * 16 + lr) * 128 + ks * 32 + lk * 8);
                acc = __builtin_amdgcn_mfma_f32_16x16x32_bf16(wf, sfrag[ks], acc, 0, 0, 0);
            }
            const int n0 = nt * 16 + lk * 4;
            if (n0 < 48) {
                float2 v0 = {fmaxf(acc[0], 0.f), fmaxf(acc[1], 0.f)};
                float2 v1 = {fmaxf(acc[2], 0.f), fmaxf(acc[3], 0.f)};
                *(float2*)(po + n0)     = v0;
                *(float2*)(po + n0 + 2) = v1;
            } else if (lk == 0) {
                float2 v0 = {fmaxf(acc[0], 0.f), fmaxf(acc[1], 0.f)};
                *(float2*)(po + 48) = v0;
            }
        }
    }

    // segment-sum of PA; forced heads every 32 rows cap the serial walk
    __syncthreads();
    if (t < 128) {
        bool head = ((t & 31) == 0) || (ps_lds[t] != ps_lds[t - 1]);
        if (head) {
            int idx = atomicAdd(&nheads, 1);
            head_list[idx] = (unsigned char)t;
        }
    }
    __syncthreads();

    const int nh = nheads;
    const unsigned int* U32c = (const unsigned int*)U16;
    for (int iw = t; iw < nh * 25; iw += 512) {
        const int r0  = head_list[iw / 25];
        const int jc  = iw % 25;
        const int seg = ps_lds[r0];
        float a0 = 0.0f, a1 = 0.0f;
        int rr = r0;
        do {
            unsigned int u = U32c[rr * 32 + (jc ^ ((rr & 7) << 2))];
            a0 += bflo(u);
            a1 += bfhi(u);
            ++rr;
        } while (rr < 128 && (rr & 31) != 0 && ps_lds[rr] == seg);
        atomicAdd(&PAsum[(size_t)seg * 50 + 2 * jc],     a0);
        atomicAdd(&PAsum[(size_t)seg * 50 + 2 * jc + 1], a1);
    }
}

// K3: A = relu(concat(AA, PAsum) @ W_A.T + b_A) (round-9 form).
__global__ __launch_bounds__(256) __attribute__((amdgpu_waves_per_eu(2, 2)))
void k_atom_final(
    const float* __restrict__ AA, const float* __restrict__ PAsum,
    const float* __restrict__ W_A, const float* __restrict__ b_A,
    float* __restrict__ Aout)
{
    const int a = blockIdx.x * 256 + threadIdx.x;
    if (a >= NATOMS) return;
    const int o0 = blockIdx.y * 25;

    float v[100];
    {
        const float2* p1 = (const float2*)(AA + (size_t)a * 50);
        const float2* p2 = (const float2*)(PAsum + (size_t)a * 50);
#pragma unroll
        for (int q = 0; q < 25; ++q) {
            float2 u1 = p1[q], u2 = p2[q];
            v[2 * q] = u1.x;      v[2 * q + 1] = u1.y;
            v[50 + 2 * q] = u2.x; v[50 + 2 * q + 1] = u2.y;
        }
    }
    float* ao = Aout + (size_t)a * 50;
#pragma unroll 2
    for (int o = o0; o < o0 + 25; ++o) {
        const float4* w4 = (const float4*)(W_A + (size_t)o * 100);
        float acc = b_A[o];
#pragma unroll
        for (int q = 0; q < 25; ++q) {
            float4 w = w4[q];
            acc = fmaf(v[4 * q + 0], w.x, acc);
            acc = fmaf(v[4 * q + 1], w.y, acc);
            acc = fmaf(v[4 * q + 2], w.z, acc);
            acc = fmaf(v[4 * q + 3], w.w, acc);
        }
        ao[o] = fmaxf(acc, 0.0f);
    }
}

extern "C" void kernel_launch(void* const* d_in, const int* in_sizes, int n_in,
                              void* d_out, int out_size, void* d_ws, size_t ws_size,
                              hipStream_t stream)
{
    const float* atom_features = (const float*)d_in[0];
    const float* pair_features = (const float*)d_in[1];
    const int*   pair_split    = (const int*)d_in[2];
    const int*   atom_to_pair  = (const int*)d_in[3];
    const float* W_AA = (const float*)d_in[4];
    const float* b_AA = (const float*)d_in[5];
    const float* W_PA = (const float*)d_in[6];
    const float* b_PA = (const float*)d_in[7];
    const float* W_A  = (const float*)d_in[8];
    const float* b_A  = (const float*)d_in[9];
    const float* W_AP = (const float*)d_in[10];
    const float* b_AP = (const float*)d_in[11];
    const float* W_PP = (const float*)d_in[12];
    const float* b_PP = (const float*)d_in[13];
    const float* W_P  = (const float*)d_in[14];
    const float* b_P  = (const float*)d_in[15];

    float* out   = (float*)d_out;
    float* A_out = out;                              // [NATOMS,50]
    float* P_out = out + (size_t)NATOMS * 50;        // [NPAIRS,50]

    float*          AA    = (float*)d_ws;                               // 5,000,000 f32
    unsigned int*   XAu   = (unsigned int*)(AA + (size_t)NATOMS * 50);  // 5,600,000 u32
    float*          PAsum = (float*)(XAu + (size_t)NATOMS * 56);        // 5,000,000 f32
    unsigned short* WPb   = (unsigned short*)(PAsum + (size_t)NATOMS * 50);  // 8192 u16
    unsigned short* WPPb  = WPb + 64 * 128;                                  // 2048 u16
    unsigned short* WPAb  = WPPb + 64 * 32;                                  // 2048 u16

    hipMemsetAsync(PAsum, 0, (size_t)NATOMS * 50 * sizeof(float), stream);

    k_wconv<<<32, 256, 0, stream>>>(W_P, b_P, W_PP, b_PP, W_PA, b_PA, WPb, WPPb, WPAb);

    k_atom_pre<<<dim3(391, 2), 256, 0, stream>>>(
        atom_features, W_AA, b_AA, W_AP, b_AP, AA, XAu);

    k_pair<<<NPAIRS / 128, 512, 0, stream>>>(
        pair_features, pair_split, atom_to_pair,
        WPb, WPPb, WPAb, XAu, PAsum, P_out);

    k_atom_final<<<dim3(391, 2), 256, 0, stream>>>(
        AA, PAsum, W_A, b_A, A_out);
}